// Round 1
// baseline (722.700 us; speedup 1.0000x reference)
//
#include <hip/hip_runtime.h>

// ---------------- constants ----------------
#define B_     16
#define WDIM   512
#define CIN_   512
#define COUT_  512
#define HH     64
#define KC     32           // channels per K-chunk
#define NCHUNK (CIN_/KC)    // 16
#define AFFINE_WG 0.044194173824159216f   // 1/sqrt(512)
#define GAIN_  1.4142135623730951f
#define CLAMP_ 256.0f

typedef __attribute__((ext_vector_type(4))) float f32x4;
typedef __attribute__((ext_vector_type(8))) short bf16x8;

__device__ __forceinline__ unsigned short f2bf(float f) {
    union { float f; unsigned u; } un; un.f = f;
    unsigned u = un.u;
    u += 0x7FFFu + ((u >> 16) & 1u);   // round-to-nearest-even
    return (unsigned short)(u >> 16);
}

// ---------------- small setup kernels ----------------

// s[b,c] = w[b,:] . aw[c,:] * AFFINE_WG + ab[c]; partial sums of s^2 per block
__global__ void k_affine(const float* __restrict__ w, const float* __restrict__ aw,
                         const float* __restrict__ ab, float* __restrict__ s,
                         float* __restrict__ part) {
    const int tid = threadIdx.x;
    const int b = blockIdx.x >> 1;
    const int c = ((blockIdx.x & 1) << 8) + tid;
    const f32x4* wr = (const f32x4*)(w + (size_t)b * WDIM);
    const f32x4* ar = (const f32x4*)(aw + (size_t)c * WDIM);
    float acc = 0.f;
    #pragma unroll 4
    for (int k = 0; k < WDIM / 4; ++k) {
        f32x4 a = ar[k], bb = wr[k];
        acc += a[0]*bb[0] + a[1]*bb[1] + a[2]*bb[2] + a[3]*bb[3];
    }
    float sv = acc * AFFINE_WG + ab[c];
    s[b * CIN_ + c] = sv;
    __shared__ float red[256];
    red[tid] = sv * sv;
    __syncthreads();
    for (int off = 128; off > 0; off >>= 1) {
        if (tid < off) red[tid] += red[tid + off];
        __syncthreads();
    }
    if (tid == 0) part[blockIdx.x] = red[0];
}

// rs = rsqrt(mean(s^2)); shat = s * rs
__global__ void k_rs_shat(const float* __restrict__ s, const float* __restrict__ part,
                          float* __restrict__ shat) {
    const int tid = threadIdx.x;
    __shared__ float rs_sh;
    if (tid == 0) {
        float t = 0.f;
        for (int i = 0; i < 32; ++i) t += part[i];
        rs_sh = rsqrtf(t * (1.0f / 8192.0f));
    }
    __syncthreads();
    const float rs = rs_sh;
    for (int i = tid; i < B_ * CIN_; i += 256) shat[i] = s[i] * rs;
}

// alpha[o] = rsqrt(mean over (c,i,j) of cw^2); Q[o,c] = alpha^2 * sum_ij cw^2
__global__ void k_wnorm(const float* __restrict__ cw, float* __restrict__ alpha,
                        float* __restrict__ Q) {
    const int o = blockIdx.x;
    const int tid = threadIdx.x;
    __shared__ float qsh[512];
    __shared__ float red[256];
    __shared__ float a_sh;
    float tot = 0.f;
    #pragma unroll
    for (int half = 0; half < 2; ++half) {
        const int c = tid + half * 256;
        const float* p = cw + ((size_t)o * 512 + c) * 9;
        float qs = 0.f;
        #pragma unroll
        for (int t = 0; t < 9; ++t) { float v = p[t]; qs += v * v; }
        qsh[c] = qs; tot += qs;
    }
    red[tid] = tot; __syncthreads();
    for (int off = 128; off > 0; off >>= 1) {
        if (tid < off) red[tid] += red[tid + off];
        __syncthreads();
    }
    if (tid == 0) { a_sh = rsqrtf(red[0] * (1.0f / 4608.0f)); alpha[o] = a_sh; }
    __syncthreads();
    const float a2 = a_sh * a_sh;
    Q[(size_t)o * 512 + tid]       = a2 * qsh[tid];
    Q[(size_t)o * 512 + tid + 256] = a2 * qsh[tid + 256];
}

// g[b,o] = alpha[o] * rsqrt(sum_c shat^2 * Q + 1e-8) * rsqrt(ema)
__global__ void k_g(const float* __restrict__ shat, const float* __restrict__ Q,
                    const float* __restrict__ alpha, const float* __restrict__ ema,
                    float* __restrict__ g) {
    const int tid = threadIdx.x;
    const int b = blockIdx.x >> 1;
    const int o = ((blockIdx.x & 1) << 8) + tid;
    const f32x4* sh = (const f32x4*)(shat + (size_t)b * CIN_);
    const f32x4* qq = (const f32x4*)(Q + (size_t)o * CIN_);
    float d = 0.f;
    #pragma unroll 4
    for (int k = 0; k < CIN_ / 4; ++k) {
        f32x4 a = sh[k], q4 = qq[k];
        d += a[0]*a[0]*q4[0] + a[1]*a[1]*q4[1] + a[2]*a[2]*q4[2] + a[3]*a[3]*q4[3];
    }
    const float ig = rsqrtf(ema[0]);
    g[b * COUT_ + o] = alpha[o] * rsqrtf(d + 1e-8f) * ig;
}

// repack conv_weight fp32 -> bf16 into conv-kernel LDS layout (incl. XOR swizzle):
// per (o-tile ot, c-chunk cc) block of 36864 bytes, byte = ((tap*2048+o*32+c)*2) ^ ((o&6)<<3)
__global__ void k_wprep(const float* __restrict__ cw, unsigned short* __restrict__ wb) {
    const int f = blockIdx.x * 256 + threadIdx.x;     // grid sized exactly 2359296
    const float v = cw[f];
    const int og  = f / 4608;
    const int rem = f - og * 4608;
    const int cg  = rem / 9;
    const int tap = rem - cg * 9;
    const int ot = og >> 6, o = og & 63, cc = cg >> 5, c = cg & 31;
    const size_t base = (size_t)(ot * 16 + cc) * 36864;   // bytes
    const int byte = ((tap * 2048 + o * 32 + c) << 1) ^ ((o & 6) << 3);
    *(unsigned short*)((char*)wb + base + byte) = f2bf(v);
}

// zero the 1-px pad ring of the 66x66 output maps
__global__ void k_border(float* __restrict__ out) {
    const int f = blockIdx.x * 256 + threadIdx.x;     // grid sized exactly 2129920
    const int bo = f / 260;
    const int r = f - bo * 260;
    int row, col;
    if (r < 66)       { row = 0;  col = r; }
    else if (r < 132) { row = 65; col = r - 66; }
    else { const int rr = r - 132; row = 1 + (rr >> 1); col = (rr & 1) ? 65 : 0; }
    out[((size_t)bo * 66 + row) * 66 + col] = 0.f;
}

// ---------------- main conv kernel ----------------
// block: 64 out-channels x 4 output rows (256 px). 4 waves, wave = 1 output row.
// K-loop: 16 chunks of 32 channels, 9 taps each, mfma_f32_16x16x32_bf16.
__global__ __launch_bounds__(256, 2) void k_conv(
    const float* __restrict__ x, const unsigned short* __restrict__ wb,
    const float* __restrict__ shat, const float* __restrict__ g,
    const float* __restrict__ bias, float* __restrict__ out) {
    __shared__ unsigned short Wlds[9 * 64 * 32];   // 36864 B, [tap][o][c] ^ o-swizzle
    __shared__ unsigned short Xlds[6 * 66 * 32];   // 25344 B, [row][col][c] ^ col-swizzle

    const int tid  = threadIdx.x;
    const int lane = tid & 63;
    const int wv   = tid >> 6;       // wave id 0..3 -> output row h0+wv
    const int l15  = lane & 15;
    const int hi   = lane >> 4;      // 0..3
    const int b  = blockIdx.z;
    const int ot = blockIdx.y;
    const int rt = blockIdx.x;
    const int h0 = rt * 4;

    const f32x4 zero4 = {0.f, 0.f, 0.f, 0.f};
    f32x4 acc[4][4];
    #pragma unroll
    for (int i = 0; i < 4; ++i)
        #pragma unroll
        for (int j = 0; j < 4; ++j) acc[i][j] = zero4;

    // zero X LDS once: pad cols (0,65) and out-of-image rows stay 0 for all chunks
    {
        unsigned int* p = (unsigned int*)Xlds;
        for (int i = tid; i < 6 * 66 * 32 / 2; i += 256) p[i] = 0u;
    }
    __syncthreads();

    for (int cc = 0; cc < NCHUNK; ++cc) {
        // ---- stage W: linear 36864B copy (data pre-swizzled in ws) ----
        {
            const f32x4* src = (const f32x4*)(wb + (size_t)(ot * 16 + cc) * 18432);
            f32x4* dst = (f32x4*)Wlds;
            #pragma unroll
            for (int r = 0; r < 9; ++r) dst[tid + r * 256] = src[tid + r * 256];
        }
        // ---- stage X: fp32 load (coalesced), *shat, ->bf16, swizzled LDS write ----
        {
            const int cbase = cc * KC;
            #pragma unroll
            for (int it = 0; it < 12; ++it) {
                const int idx = tid + it * 256;          // < 3072
                const int c   = idx / 96;
                const int rem = idx - c * 96;
                const int row = rem >> 4;                // 0..5
                const int seg = rem & 15;                // 16B segment along w
                const int h_in = h0 - 1 + row;
                if ((unsigned)h_in < 64u) {
                    const f32x4 v = *(const f32x4*)(
                        x + (((size_t)(b * CIN_ + cbase + c) * HH + h_in) << 6) + seg * 4);
                    const float sc = shat[b * CIN_ + cbase + c];
                    #pragma unroll
                    for (int q = 0; q < 4; ++q) {
                        const int col = 1 + seg * 4 + q;         // lds col = img col + 1
                        int byte = (((row * 66 + col) << 5) + c) << 1;
                        byte ^= ((col & 6) << 3);
                        *(unsigned short*)((char*)Xlds + byte) = f2bf(v[q] * sc);
                    }
                }
            }
        }
        __syncthreads();

        // ---- compute: 9 taps x 16 mfma ----
        #pragma unroll
        for (int tap = 0; tap < 9; ++tap) {
            const int ti = tap / 3, tj = tap - ti * 3;
            bf16x8 af[4];
            #pragma unroll
            for (int mi = 0; mi < 4; ++mi) {
                const int o = mi * 16 + l15;
                int byte = (tap << 12) + (o << 6) + (hi << 4);
                byte ^= ((o & 6) << 3);
                af[mi] = *(const bf16x8*)((const char*)Wlds + byte);
            }
            bf16x8 bg[4];
            const int row = wv + ti;
            #pragma unroll
            for (int ni = 0; ni < 4; ++ni) {
                const int col = ni * 16 + l15 + tj;
                int byte = (((row * 66 + col) << 5) + (hi << 3)) << 1;
                byte ^= ((col & 6) << 3);
                bg[ni] = *(const bf16x8*)((const char*)Xlds + byte);
            }
            #pragma unroll
            for (int mi = 0; mi < 4; ++mi)
                #pragma unroll
                for (int ni = 0; ni < 4; ++ni)
                    acc[mi][ni] = __builtin_amdgcn_mfma_f32_16x16x32_bf16(
                        af[mi], bg[ni], acc[mi][ni], 0, 0, 0);
        }
        if (cc != NCHUNK - 1) __syncthreads();
    }

    // ---- epilogue: *G, +bias, lrelu*gain, clamp, store interior ----
    {
        const int obase = ot * 64;
        const int orow = h0 + wv + 1;
        #pragma unroll
        for (int mi = 0; mi < 4; ++mi) {
            #pragma unroll
            for (int r = 0; r < 4; ++r) {
                const int o = obase + mi * 16 + hi * 4 + r;
                const float gg = g[b * COUT_ + o];
                const float bb = bias[o];
                float* op = out + ((size_t)(b * COUT_ + o) * 66 + orow) * 66;
                #pragma unroll
                for (int ni = 0; ni < 4; ++ni) {
                    float v = acc[mi][ni][r] * gg + bb;
                    v = (v >= 0.f ? v : v * 0.2f) * GAIN_;
                    v = fminf(fmaxf(v, -CLAMP_), CLAMP_);
                    op[ni * 16 + l15 + 1] = v;
                }
            }
        }
    }
}

// ---------------- launcher ----------------
extern "C" void kernel_launch(void* const* d_in, const int* in_sizes, int n_in,
                              void* d_out, int out_size, void* d_ws, size_t ws_size,
                              hipStream_t stream) {
    const float* x    = (const float*)d_in[0];
    const float* w    = (const float*)d_in[1];
    const float* aw   = (const float*)d_in[2];
    const float* ab   = (const float*)d_in[3];
    const float* cw   = (const float*)d_in[4];
    const float* bias = (const float*)d_in[5];
    const float* ema  = (const float*)d_in[6];
    float* out = (float*)d_out;

    float* wsf   = (float*)d_ws;
    float* s     = wsf;                 // 8192
    float* part  = wsf + 8192;          // 32
    float* shat  = wsf + 8320;          // 8192
    float* alpha = wsf + 16512;         // 512
    float* Q     = wsf + 17024;         // 262144
    float* g     = wsf + 279168;        // 8192
    unsigned short* wb = (unsigned short*)((char*)d_ws + 1179648);  // 4718592 B

    k_affine <<<32, 256, 0, stream>>>(w, aw, ab, s, part);
    k_rs_shat<<<1, 256, 0, stream>>>(s, part, shat);
    k_wnorm  <<<512, 256, 0, stream>>>(cw, alpha, Q);
    k_g      <<<32, 256, 0, stream>>>(shat, Q, alpha, ema, g);
    k_wprep  <<<9216, 256, 0, stream>>>(cw, wb);
    k_border <<<8320, 256, 0, stream>>>(out);
    k_conv   <<<dim3(16, 8, 16), 256, 0, stream>>>(x, wb, shat, g, bias, out);
}

// Round 2
// 346.260 us; speedup vs baseline: 2.0872x; 2.0872x over previous
//
#include <hip/hip_runtime.h>

// ---------------- constants ----------------
#define B_     16
#define WDIM   512
#define CIN_   512
#define COUT_  512
#define HH     64
#define KC     32           // channels per K-chunk
#define NCHUNK (CIN_/KC)    // 16
#define AFFINE_WG 0.044194173824159216f   // 1/sqrt(512)
#define GAIN_  1.4142135623730951f
#define CLAMP_ 256.0f

typedef __attribute__((ext_vector_type(4))) float f32x4;
typedef __attribute__((ext_vector_type(8))) short bf16x8;
typedef __attribute__((ext_vector_type(8))) unsigned short u16x8;

__device__ __forceinline__ unsigned short f2bf(float f) {
    union { float f; unsigned u; } un; un.f = f;
    unsigned u = un.u;
    u += 0x7FFFu + ((u >> 16) & 1u);   // round-to-nearest-even
    return (unsigned short)(u >> 16);
}

__device__ __forceinline__ void gl_lds16(const void* g, void* l) {
    __builtin_amdgcn_global_load_lds(
        reinterpret_cast<const __attribute__((address_space(1))) unsigned int*>(
            reinterpret_cast<uintptr_t>(g)),
        reinterpret_cast<__attribute__((address_space(3))) unsigned int*>(
            reinterpret_cast<uintptr_t>(l)),
        16, 0, 0);
}

// ---------------- small setup kernels ----------------

// s[b,c] = w[b,:] . aw[c,:] * AFFINE_WG + ab[c]; partial sums of s^2 per block
__global__ void k_affine(const float* __restrict__ w, const float* __restrict__ aw,
                         const float* __restrict__ ab, float* __restrict__ s,
                         float* __restrict__ part) {
    const int tid = threadIdx.x;
    const int b = blockIdx.x >> 1;
    const int c = ((blockIdx.x & 1) << 8) + tid;
    const f32x4* wr = (const f32x4*)(w + (size_t)b * WDIM);
    const f32x4* ar = (const f32x4*)(aw + (size_t)c * WDIM);
    float acc = 0.f;
    #pragma unroll 4
    for (int k = 0; k < WDIM / 4; ++k) {
        f32x4 a = ar[k], bb = wr[k];
        acc += a[0]*bb[0] + a[1]*bb[1] + a[2]*bb[2] + a[3]*bb[3];
    }
    float sv = acc * AFFINE_WG + ab[c];
    s[b * CIN_ + c] = sv;
    __shared__ float red[256];
    red[tid] = sv * sv;
    __syncthreads();
    for (int off = 128; off > 0; off >>= 1) {
        if (tid < off) red[tid] += red[tid + off];
        __syncthreads();
    }
    if (tid == 0) part[blockIdx.x] = red[0];
}

// rs = rsqrt(mean(s^2)); shat = s * rs
__global__ void k_rs_shat(const float* __restrict__ s, const float* __restrict__ part,
                          float* __restrict__ shat) {
    const int tid = threadIdx.x;
    __shared__ float rs_sh;
    if (tid == 0) {
        float t = 0.f;
        for (int i = 0; i < 32; ++i) t += part[i];
        rs_sh = rsqrtf(t * (1.0f / 8192.0f));
    }
    __syncthreads();
    const float rs = rs_sh;
    for (int i = tid; i < B_ * CIN_; i += 256) shat[i] = s[i] * rs;
}

// alpha[o] = rsqrt(mean over (c,i,j) of cw^2); Q[o,c] = alpha^2 * sum_ij cw^2
__global__ void k_wnorm(const float* __restrict__ cw, float* __restrict__ alpha,
                        float* __restrict__ Q) {
    const int o = blockIdx.x;
    const int tid = threadIdx.x;
    __shared__ float qsh[512];
    __shared__ float red[256];
    __shared__ float a_sh;
    float tot = 0.f;
    #pragma unroll
    for (int half = 0; half < 2; ++half) {
        const int c = tid + half * 256;
        const float* p = cw + ((size_t)o * 512 + c) * 9;
        float qs = 0.f;
        #pragma unroll
        for (int t = 0; t < 9; ++t) { float v = p[t]; qs += v * v; }
        qsh[c] = qs; tot += qs;
    }
    red[tid] = tot; __syncthreads();
    for (int off = 128; off > 0; off >>= 1) {
        if (tid < off) red[tid] += red[tid + off];
        __syncthreads();
    }
    if (tid == 0) { a_sh = rsqrtf(red[0] * (1.0f / 4608.0f)); alpha[o] = a_sh; }
    __syncthreads();
    const float a2 = a_sh * a_sh;
    Q[(size_t)o * 512 + tid]       = a2 * qsh[tid];
    Q[(size_t)o * 512 + tid + 256] = a2 * qsh[tid + 256];
}

// g[b,o] = alpha[o] * rsqrt(sum_c shat^2 * Q + 1e-8) * rsqrt(ema)
__global__ void k_g(const float* __restrict__ shat, const float* __restrict__ Q,
                    const float* __restrict__ alpha, const float* __restrict__ ema,
                    float* __restrict__ g) {
    const int tid = threadIdx.x;
    const int b = blockIdx.x >> 1;
    const int o = ((blockIdx.x & 1) << 8) + tid;
    const f32x4* sh = (const f32x4*)(shat + (size_t)b * CIN_);
    const f32x4* qq = (const f32x4*)(Q + (size_t)o * CIN_);
    float d = 0.f;
    #pragma unroll 4
    for (int k = 0; k < CIN_ / 4; ++k) {
        f32x4 a = sh[k], q4 = qq[k];
        d += a[0]*a[0]*q4[0] + a[1]*a[1]*q4[1] + a[2]*a[2]*q4[2] + a[3]*a[3]*q4[3];
    }
    const float ig = rsqrtf(ema[0]);
    g[b * COUT_ + o] = alpha[o] * rsqrtf(d + 1e-8f) * ig;
}

// repack conv_weight fp32 -> bf16 into conv-kernel LDS layout (incl. XOR swizzle):
// per (o-tile ot, c-chunk cc) block of 36864 bytes, byte = ((tap*2048+o*32+c)*2) ^ ((o&6)<<3)
__global__ void k_wprep(const float* __restrict__ cw, unsigned short* __restrict__ wb) {
    const int f = blockIdx.x * 256 + threadIdx.x;     // grid sized exactly 2359296
    const float v = cw[f];
    const int og  = f / 4608;
    const int rem = f - og * 4608;
    const int cg  = rem / 9;
    const int tap = rem - cg * 9;
    const int ot = og >> 6, o = og & 63, cc = cg >> 5, c = cg & 31;
    const size_t base = (size_t)(ot * 16 + cc) * 36864;   // bytes
    const int byte = ((tap * 2048 + o * 32 + c) << 1) ^ ((o & 6) << 3);
    *(unsigned short*)((char*)wb + base + byte) = f2bf(v);
}

// x fp32 [b][c][h][w] -> xbf bf16, scaled by shat, channel-interleaved + INVERSE-swizzled
// so that a linear global_load_lds of one row-slab yields the conv kernel's swizzled
// X layout. Per (b,cc): 64 rows x 4096 B; within a row, 16B slot at offset ro16*16
// holds channels c0..c0+7 of column `col`, where (col,c0) invert
//   full = ro16*16 + 64 = (col*64 + c0*2) ^ ((col&6)<<3)
__global__ void k_xprep(const float* __restrict__ x, const float* __restrict__ shat,
                        unsigned short* __restrict__ xbf) {
    const int slot = blockIdx.x * 256 + threadIdx.x;   // grid exactly 4194304 slots
    const int pair = slot >> 14;           // b*16+cc
    const int rem  = slot & 16383;
    const int row  = rem >> 8;             // 0..63
    const int ro16 = rem & 255;
    const int full = ro16 * 16 + 64;
    const int col  = full >> 6;            // 1..64 (lds col; img col = col-1)
    const int c0   = ((full & 63) ^ ((col & 6) << 3)) >> 1;   // 0,8,16,24
    const int b    = pair >> 4, cc = pair & 15;
    const int cbase = cc * 32 + c0;
    const float* src = x + (((size_t)(b * CIN_ + cbase)) * HH + row) * HH + (col - 1);
    const float* sp  = shat + b * CIN_ + cbase;
    u16x8 v;
    #pragma unroll
    for (int j = 0; j < 8; ++j)
        v[j] = f2bf(src[(size_t)j * 4096] * sp[j]);
    *(u16x8*)(xbf + (size_t)slot * 8) = v;
}

// zero the 1-px pad ring of the 66x66 output maps
__global__ void k_border(float* __restrict__ out) {
    const int f = blockIdx.x * 256 + threadIdx.x;     // grid sized exactly 2129920
    const int bo = f / 260;
    const int r = f - bo * 260;
    int row, col;
    if (r < 66)       { row = 0;  col = r; }
    else if (r < 132) { row = 65; col = r - 66; }
    else { const int rr = r - 132; row = 1 + (rr >> 1); col = (rr & 1) ? 65 : 0; }
    out[((size_t)bo * 66 + row) * 66 + col] = 0.f;
}

// ---------------- fast conv kernel: pure global_load_lds staging ----------------
// block: 64 out-channels x 4 output rows (256 px). 4 waves, wave = 1 output row.
__global__ __launch_bounds__(256, 2) void k_conv2(
    const unsigned short* __restrict__ xbf, const unsigned short* __restrict__ wb,
    const float* __restrict__ g, const float* __restrict__ bias,
    float* __restrict__ out) {
    __shared__ unsigned short Wlds[9 * 64 * 32];   // 36864 B, [tap][o][c] ^ o-swizzle
    __shared__ unsigned short Xlds[6 * 66 * 32];   // 25344 B, [row][col][c] ^ col-swizzle

    const int tid  = threadIdx.x;
    const int lane = tid & 63;
    const int wv   = tid >> 6;       // wave id 0..3 -> output row h0+wv
    const int l15  = lane & 15;
    const int hi   = lane >> 4;      // 0..3
    const int b  = blockIdx.z;
    const int ot = blockIdx.y;
    const int rt = blockIdx.x;
    const int h0 = rt * 4;

    const f32x4 zero4 = {0.f, 0.f, 0.f, 0.f};
    f32x4 acc[4][4];
    #pragma unroll
    for (int i = 0; i < 4; ++i)
        #pragma unroll
        for (int j = 0; j < 4; ++j) acc[i][j] = zero4;

    // zero X LDS once: pad cols (0,65) and out-of-image rows stay 0 for all chunks
    {
        unsigned int* p = (unsigned int*)Xlds;
        for (int i = tid; i < 6 * 66 * 32 / 2; i += 256) p[i] = 0u;
    }
    __syncthreads();

    const char* wsrc0 = (const char*)wb + (size_t)ot * 16 * 36864;
    const char* xsrc0 = (const char*)xbf + (size_t)b * 16 * 262144;   // 64*4096 per (b,cc)

    for (int cc = 0; cc < NCHUNK; ++cc) {
        // ---- stage W: 9 x 4096B linear slabs (pre-swizzled in ws) ----
        const char* wsrc = wsrc0 + (size_t)cc * 36864;
        #pragma unroll
        for (int r = 0; r < 9; ++r)
            gl_lds16(wsrc + r * 4096 + tid * 16,
                     (char*)Wlds + r * 4096 + wv * 1024);
        // ---- stage X: up to 6 x 4096B row slabs into cols 1..64 (pre-swizzled) ----
        const char* xsrc = xsrc0 + (size_t)cc * 262144;
        #pragma unroll
        for (int r = 0; r < 6; ++r) {
            const int h_in = h0 - 1 + r;
            if ((unsigned)h_in < 64u)
                gl_lds16(xsrc + (size_t)h_in * 4096 + tid * 16,
                         (char*)Xlds + r * 4224 + 64 + wv * 1024);
        }
        __syncthreads();

        // ---- compute: 9 taps x 16 mfma per wave ----
        #pragma unroll
        for (int tap = 0; tap < 9; ++tap) {
            const int ti = tap / 3, tj = tap - ti * 3;
            bf16x8 af[4];
            #pragma unroll
            for (int mi = 0; mi < 4; ++mi) {
                const int o = mi * 16 + l15;
                int byte = (tap << 12) + (o << 6) + (hi << 4);
                byte ^= ((o & 6) << 3);
                af[mi] = *(const bf16x8*)((const char*)Wlds + byte);
            }
            bf16x8 bg[4];
            const int row = wv + ti;
            #pragma unroll
            for (int ni = 0; ni < 4; ++ni) {
                const int col = ni * 16 + l15 + tj;
                int byte = (((row * 66 + col) << 5) + (hi << 3)) << 1;
                byte ^= ((col & 6) << 3);
                bg[ni] = *(const bf16x8*)((const char*)Xlds + byte);
            }
            #pragma unroll
            for (int mi = 0; mi < 4; ++mi)
                #pragma unroll
                for (int ni = 0; ni < 4; ++ni)
                    acc[mi][ni] = __builtin_amdgcn_mfma_f32_16x16x32_bf16(
                        af[mi], bg[ni], acc[mi][ni], 0, 0, 0);
        }
        if (cc != NCHUNK - 1) __syncthreads();
    }

    // ---- epilogue: *G, +bias, lrelu*gain, clamp, store interior ----
    {
        const int obase = ot * 64;
        const int orow = h0 + wv + 1;
        #pragma unroll
        for (int mi = 0; mi < 4; ++mi) {
            #pragma unroll
            for (int r = 0; r < 4; ++r) {
                const int o = obase + mi * 16 + hi * 4 + r;
                const float gg = g[b * COUT_ + o];
                const float bb = bias[o];
                float* op = out + ((size_t)(b * COUT_ + o) * 66 + orow) * 66;
                #pragma unroll
                for (int ni = 0; ni < 4; ++ni) {
                    float v = acc[mi][ni][r] * gg + bb;
                    v = (v >= 0.f ? v : v * 0.2f) * GAIN_;
                    v = fminf(fmaxf(v, -CLAMP_), CLAMP_);
                    op[ni * 16 + l15 + 1] = v;
                }
            }
        }
    }
}

// ---------------- fallback conv kernel (round-1, reg-staged) ----------------
__global__ __launch_bounds__(256, 2) void k_conv(
    const float* __restrict__ x, const unsigned short* __restrict__ wb,
    const float* __restrict__ shat, const float* __restrict__ g,
    const float* __restrict__ bias, float* __restrict__ out) {
    __shared__ unsigned short Wlds[9 * 64 * 32];
    __shared__ unsigned short Xlds[6 * 66 * 32];

    const int tid  = threadIdx.x;
    const int lane = tid & 63;
    const int wv   = tid >> 6;
    const int l15  = lane & 15;
    const int hi   = lane >> 4;
    const int b  = blockIdx.z;
    const int ot = blockIdx.y;
    const int rt = blockIdx.x;
    const int h0 = rt * 4;

    const f32x4 zero4 = {0.f, 0.f, 0.f, 0.f};
    f32x4 acc[4][4];
    #pragma unroll
    for (int i = 0; i < 4; ++i)
        #pragma unroll
        for (int j = 0; j < 4; ++j) acc[i][j] = zero4;

    {
        unsigned int* p = (unsigned int*)Xlds;
        for (int i = tid; i < 6 * 66 * 32 / 2; i += 256) p[i] = 0u;
    }
    __syncthreads();

    for (int cc = 0; cc < NCHUNK; ++cc) {
        {
            const f32x4* src = (const f32x4*)(wb + (size_t)(ot * 16 + cc) * 18432);
            f32x4* dst = (f32x4*)Wlds;
            #pragma unroll
            for (int r = 0; r < 9; ++r) dst[tid + r * 256] = src[tid + r * 256];
        }
        {
            const int cbase = cc * KC;
            #pragma unroll
            for (int it = 0; it < 12; ++it) {
                const int idx = tid + it * 256;
                const int c   = idx / 96;
                const int rem = idx - c * 96;
                const int row = rem >> 4;
                const int seg = rem & 15;
                const int h_in = h0 - 1 + row;
                if ((unsigned)h_in < 64u) {
                    const f32x4 v = *(const f32x4*)(
                        x + (((size_t)(b * CIN_ + cbase + c) * HH + h_in) << 6) + seg * 4);
                    const float sc = shat[b * CIN_ + cbase + c];
                    #pragma unroll
                    for (int q = 0; q < 4; ++q) {
                        const int col = 1 + seg * 4 + q;
                        int byte = (((row * 66 + col) << 5) + c) << 1;
                        byte ^= ((col & 6) << 3);
                        *(unsigned short*)((char*)Xlds + byte) = f2bf(v[q] * sc);
                    }
                }
            }
        }
        __syncthreads();

        #pragma unroll
        for (int tap = 0; tap < 9; ++tap) {
            const int ti = tap / 3, tj = tap - ti * 3;
            bf16x8 af[4];
            #pragma unroll
            for (int mi = 0; mi < 4; ++mi) {
                const int o = mi * 16 + l15;
                int byte = (tap << 12) + (o << 6) + (hi << 4);
                byte ^= ((o & 6) << 3);
                af[mi] = *(const bf16x8*)((const char*)Wlds + byte);
            }
            bf16x8 bg[4];
            const int row = wv + ti;
            #pragma unroll
            for (int ni = 0; ni < 4; ++ni) {
                const int col = ni * 16 + l15 + tj;
                int byte = (((row * 66 + col) << 5) + (hi << 3)) << 1;
                byte ^= ((col & 6) << 3);
                bg[ni] = *(const bf16x8*)((const char*)Xlds + byte);
            }
            #pragma unroll
            for (int mi = 0; mi < 4; ++mi)
                #pragma unroll
                for (int ni = 0; ni < 4; ++ni)
                    acc[mi][ni] = __builtin_amdgcn_mfma_f32_16x16x32_bf16(
                        af[mi], bg[ni], acc[mi][ni], 0, 0, 0);
        }
        if (cc != NCHUNK - 1) __syncthreads();
    }

    {
        const int obase = ot * 64;
        const int orow = h0 + wv + 1;
        #pragma unroll
        for (int mi = 0; mi < 4; ++mi) {
            #pragma unroll
            for (int r = 0; r < 4; ++r) {
                const int o = obase + mi * 16 + hi * 4 + r;
                const float gg = g[b * COUT_ + o];
                const float bb = bias[o];
                float* op = out + ((size_t)(b * COUT_ + o) * 66 + orow) * 66;
                #pragma unroll
                for (int ni = 0; ni < 4; ++ni) {
                    float v = acc[mi][ni][r] * gg + bb;
                    v = (v >= 0.f ? v : v * 0.2f) * GAIN_;
                    v = fminf(fmaxf(v, -CLAMP_), CLAMP_);
                    op[ni * 16 + l15 + 1] = v;
                }
            }
        }
    }
}

// ---------------- launcher ----------------
extern "C" void kernel_launch(void* const* d_in, const int* in_sizes, int n_in,
                              void* d_out, int out_size, void* d_ws, size_t ws_size,
                              hipStream_t stream) {
    const float* x    = (const float*)d_in[0];
    const float* w    = (const float*)d_in[1];
    const float* aw   = (const float*)d_in[2];
    const float* ab   = (const float*)d_in[3];
    const float* cw   = (const float*)d_in[4];
    const float* bias = (const float*)d_in[5];
    const float* ema  = (const float*)d_in[6];
    float* out = (float*)d_out;

    float* wsf   = (float*)d_ws;
    float* s     = wsf;                 // 8192
    float* part  = wsf + 8192;          // 32
    float* shat  = wsf + 8320;          // 8192
    float* alpha = wsf + 16512;         // 512
    float* Q     = wsf + 17024;         // 262144
    float* g     = wsf + 279168;        // 8192
    unsigned short* wb  = (unsigned short*)((char*)d_ws + 1179648);  // 4718592 B
    unsigned short* xbf = (unsigned short*)((char*)d_ws + 5898240);  // 67108864 B
    const size_t need = 5898240u + 67108864u;

    k_affine <<<32, 256, 0, stream>>>(w, aw, ab, s, part);
    k_rs_shat<<<1, 256, 0, stream>>>(s, part, shat);
    k_wnorm  <<<512, 256, 0, stream>>>(cw, alpha, Q);
    k_g      <<<32, 256, 0, stream>>>(shat, Q, alpha, ema, g);
    k_wprep  <<<9216, 256, 0, stream>>>(cw, wb);
    k_border <<<8320, 256, 0, stream>>>(out);

    if (ws_size >= need) {
        k_xprep <<<16384, 256, 0, stream>>>(x, shat, xbf);
        k_conv2 <<<dim3(16, 8, 16), 256, 0, stream>>>(xbf, wb, g, bias, out);
    } else {
        k_conv  <<<dim3(16, 8, 16), 256, 0, stream>>>(x, wb, shat, g, bias, out);
    }
}